// Round 1
// 154.547 us; speedup vs baseline: 1.0006x; 1.0006x over previous
//
#include <hip/hip_runtime.h>
#include <stdint.h>

#define Nn 4
#define Cc 64
#define LL 4096   // H*W
#define KK 256    // feature dim: 64 channels * 4 causal taps
#define TRI2 528  // 32*33/2 triangular 128x128 tile pairs per batch

typedef _Float16 half8 __attribute__((ext_vector_type(8)));
typedef float f32x16 __attribute__((ext_vector_type(16)));
typedef float f4a __attribute__((ext_vector_type(4), aligned(4)));

__device__ __forceinline__ unsigned f2ord(float f) {
    unsigned u = __float_as_uint(f);
    return u ^ ((u & 0x80000000u) ? 0xFFFFFFFFu : 0x80000000u);
}
__device__ __forceinline__ float ord2f(unsigned o) {
    unsigned u = (o & 0x80000000u) ? (o ^ 0x80000000u) : ~o;
    return __uint_as_float(u);
}
__device__ __forceinline__ unsigned short h2u(_Float16 h) {
    union { _Float16 f; unsigned short u; } x; x.f = h; return x.u;
}

// Kernel 1: normalized masked context vectors, split fp16 hi/lo, both pre-scaled:
//   Vh' = 2048*fp16(v)  (exact pow2),  Vl = fp16((v - fp16(v)) * 2048)
// Vh layout: [n][l][k] row-major (staged through LDS in simmax).
// Vl layout: MFMA-FRAGMENT-PACKED so simmax loads lo frags straight from L2:
//   index = (((n*128 + (l>>5))*16 + k16) * 64 + (l&31) + 32*((k>>3)&1)) * 8 + (k&7)
//   i.e. per (rowblk32, k16-chunk) a 1KB block where lane = (k8-half)*32 + row
//   reads its 16B at blockbase + lane*16B  (identity mapping, fully coalesced).
// XCD-pinned and zeroes its slice of `best`.
__global__ __launch_bounds__(256) void build_v(const float* __restrict__ yhat,
                                               unsigned short* __restrict__ VhT,
                                               unsigned short* __restrict__ VlT,
                                               unsigned long long* __restrict__ best) {
    int blk = blockIdx.x;                       // 0..1023
    int xcd = blk & 7;
    int n = xcd >> 1;
    int i64 = (blk >> 3) + (xcd & 1) * 128;     // 0..255; block covers l = i64*16 ..+16
    int tid = threadIdx.x;
    if (tid < 16) best[(size_t)n * LL + i64 * 16 + tid] = 0ull;

    int cg = tid & 15;           // channel group 0..15 (4 channels each) == k16 chunk
    int l = i64 * 16 + (tid >> 4);
    int y = l >> 6, x = l & 63;
    const float* src = yhat + (size_t)n * (Cc * LL);

    float vals[16];
    float sumsq = 0.f;
#pragma unroll
    for (int ci = 0; ci < 4; ++ci) {
        const float* p = src + (cg * 4 + ci) * LL;
        float t0 = (y > 0 && x > 0)  ? p[l - 65] : 0.f;
        float t1 = (y > 0)           ? p[l - 64] : 0.f;
        float t2 = (y > 0 && x < 63) ? p[l - 63] : 0.f;
        float t3 = (x > 0)           ? p[l - 1]  : 0.f;
        vals[ci * 4 + 0] = t0; vals[ci * 4 + 1] = t1;
        vals[ci * 4 + 2] = t2; vals[ci * 4 + 3] = t3;
        sumsq += t0 * t0 + t1 * t1 + t2 * t2 + t3 * t3;
    }
    sumsq += __shfl_xor(sumsq, 1, 64);
    sumsq += __shfl_xor(sumsq, 2, 64);
    sumsq += __shfl_xor(sumsq, 4, 64);
    sumsq += __shfl_xor(sumsq, 8, 64);
    float inv = 1.f / fmaxf(sqrtf(sumsq), 1e-12f);

    size_t nl = (size_t)n * LL + l;
    unsigned short* dh = VhT + nl * KK + cg * 16;
    // fragment-packed lo destination: 1KB chunk base + row slot
    unsigned short* dl = VlT + ((((size_t)n * 128 + (l >> 5)) * 16 + cg) << 9) + (l & 31) * 8;
#pragma unroll
    for (int ci = 0; ci < 4; ++ci) {
        ushort4 hv, lv;
        unsigned short* ph = &hv.x;
        unsigned short* pl = &lv.x;
#pragma unroll
        for (int tp = 0; tp < 4; ++tp) {
            float v = vals[ci * 4 + tp] * inv;
            _Float16 h = (fabsf(v) < 6.1035e-5f) ? (_Float16)0 : (_Float16)v;
            _Float16 lo = (_Float16)((v - (float)h) * 2048.0f);
            ph[tp] = h2u(h * (_Float16)2048.0f);   // exact pow2 scale
            pl[tp] = h2u(lo);
        }
        *(ushort4*)(dh + ci * 4) = hv;
        // k%16 = (ci>>1)*8 + (ci&1)*4 + tp ; half-slot (ci>>1) is 32 lanes (=256 halves) away
        *(ushort4*)(dl + (ci >> 1) * 256 + (ci & 1) * 4) = lv;
    }
}

// Kernel 2: triangular 128x128-tiled similarity-max via split-fp16 32x32x16 MFMA.
// acc = Al'Bh' + Ah'Bl + Ah'Bh' = 2^22 * v1.v2 ; val = acc * 2^-22.
// Restructured vs prior version:
//  - lo operands (Al,Bl) bypass LDS: loaded per-lane direct from fragment-packed Vl
//    (halves LDS traffic; loads are 1KB/instr fully coalesced, L2-resident)
//  - hi staging double-buffered in same 32KB (2 x (Ah|Bh) 128x32), prefetched one
//    kstep ahead -> global latency hides under MFMA; ONE barrier per kstep (was 2)
//  - s_setprio(1) around MFMA cluster
// Accumulation order and operand values preserved bit-exactly vs prior version.
// 32x32x16 layouts: A/B row(col)=lane&31, k=(lane>>5)*8+j;
// C/D: col=lane&31, row=(reg&3)+8*(reg>>2)+4*(lane>>5).
__global__ __launch_bounds__(256) void simmax(const unsigned short* __restrict__ Vh,
                                              const unsigned short* __restrict__ Vl,
                                              unsigned long long* __restrict__ best) {
    __shared__ __align__(16) unsigned short S[16384];   // 32 KB: 2 bufs x (Ah|Bh)

    int bx = blockIdx.x;              // 0..2111
    int xcd = bx & 7, idx = bx >> 3;  // XCD-pin: each XCD owns half of one batch
    int n = xcd >> 1;
    int t = (xcd & 1) * 264 + idx;    // 0..527
    int j = (int)((sqrtf(8.f * (float)t + 1.f) - 1.f) * 0.5f);
    while ((j + 1) * (j + 2) / 2 <= t) ++j;
    while (j * (j + 1) / 2 > t) --j;
    int i = t - j * (j + 1) / 2;
    int l0 = i * 128, m0 = j * 128;

    const unsigned short* VhB = Vh + (size_t)n * (LL * KK);
    const unsigned short* VlB = Vl + (size_t)n * (LL * KK);

    int tid = threadIdx.x;
    int w = tid >> 6, lane = tid & 63;
    int r5 = lane & 31, h5 = lane >> 5;
    int rw = (w & 1) * 64;    // wave rows (l)
    int cw = (w >> 1) * 64;   // wave cols (m)
    bool skip = (i == j) && (rw == 64) && (cw == 0);  // fully l>m

    f32x16 acc[2][2];
#pragma unroll
    for (int r = 0; r < 2; ++r)
#pragma unroll
        for (int c = 0; c < 2; ++c) acc[r][c] = (f32x16)0.f;

    int srow = tid >> 2;          // 0..63
    int scl = tid & 3;            // global chunk 0..3 (8 halves each) - coalesced
    int sp = (scl ^ ((srow >> 1) & 3)) * 8;   // physical chunk offset (halves)
    int shg = scl * 8;            // global offset in halves
    int sfr = (r5 >> 1) & 3;      // fragment-row swizzle

    // lo fragment bases: chunk index = (rowblk*16 + k16), 1KB (512 halves) each
    const unsigned short* loA = VlB + ((size_t)((l0 + rw) >> 5) << 13) + lane * 8;
    const unsigned short* loB = VlB + ((size_t)((m0 + cw) >> 5) << 13) + lane * 8;

    // prologue: stage k0=0 hi tile into buf0
    {
        uint4 a0 = *(const uint4*)(VhB + (size_t)(l0 + srow) * KK + shg);
        uint4 a1 = *(const uint4*)(VhB + (size_t)(l0 + 64 + srow) * KK + shg);
        uint4 b0 = *(const uint4*)(VhB + (size_t)(m0 + srow) * KK + shg);
        uint4 b1 = *(const uint4*)(VhB + (size_t)(m0 + 64 + srow) * KK + shg);
        *(uint4*)&S[srow * 32 + sp]               = a0;
        *(uint4*)&S[(64 + srow) * 32 + sp]        = a1;
        *(uint4*)&S[4096 + srow * 32 + sp]        = b0;
        *(uint4*)&S[4096 + (64 + srow) * 32 + sp] = b1;
    }
    __syncthreads();

#pragma unroll
    for (int kt = 0; kt < 8; ++kt) {
        const int k0 = kt * 32;
        const int kb = kt * 2;                 // k16 chunk base
        const int cur = (kt & 1) * 8192;       // read buffer (halves)
        const int nxt = 8192 - cur;            // write buffer

        // 1) lo fragment loads, first-use order (needed by pass 1/2)
        half8 fal[2][2], fbl[2][2];
        if (!skip) {
#pragma unroll
            for (int kc = 0; kc < 2; ++kc)
#pragma unroll
                for (int r = 0; r < 2; ++r)
                    fal[r][kc] = *(const half8*)(loA + ((r * 16 + kb + kc) << 9));
#pragma unroll
            for (int kc = 0; kc < 2; ++kc)
#pragma unroll
                for (int r = 0; r < 2; ++r)
                    fbl[r][kc] = *(const half8*)(loB + ((r * 16 + kb + kc) << 9));
        }

        // 2) hi prefetch for next kstep (consumed after MFMA cluster)
        uint4 na0, na1, nb0, nb1;
        if (kt < 7) {
            const int kn = k0 + 32;
            na0 = *(const uint4*)(VhB + (size_t)(l0 + srow) * KK + kn + shg);
            na1 = *(const uint4*)(VhB + (size_t)(l0 + 64 + srow) * KK + kn + shg);
            nb0 = *(const uint4*)(VhB + (size_t)(m0 + srow) * KK + kn + shg);
            nb1 = *(const uint4*)(VhB + (size_t)(m0 + 64 + srow) * KK + kn + shg);
        }

        if (!skip) {
            // 3) hi fragments from LDS buf[cur]
            half8 fah[2][2], fbh[2][2];
#pragma unroll
            for (int r = 0; r < 2; ++r)
#pragma unroll
                for (int kc = 0; kc < 2; ++kc) {
                    int pc = ((kc * 2 + h5) ^ sfr) * 8;
                    fbh[r][kc] = *(half8*)&S[cur + 4096 + (cw + r * 32 + r5) * 32 + pc];
                    fah[r][kc] = *(half8*)&S[cur + (rw + r * 32 + r5) * 32 + pc];
                }
            // 4) MFMA cluster — accumulation order identical to prior version
            __builtin_amdgcn_s_setprio(1);
#pragma unroll
            for (int kc = 0; kc < 2; ++kc)
#pragma unroll
                for (int r = 0; r < 2; ++r)
#pragma unroll
                    for (int c = 0; c < 2; ++c)
                        acc[r][c] = __builtin_amdgcn_mfma_f32_32x32x16_f16(fal[r][kc], fbh[c][kc], acc[r][c], 0, 0, 0);
#pragma unroll
            for (int kc = 0; kc < 2; ++kc)
#pragma unroll
                for (int r = 0; r < 2; ++r)
#pragma unroll
                    for (int c = 0; c < 2; ++c)
                        acc[r][c] = __builtin_amdgcn_mfma_f32_32x32x16_f16(fah[r][kc], fbl[c][kc], acc[r][c], 0, 0, 0);
#pragma unroll
            for (int kc = 0; kc < 2; ++kc)
#pragma unroll
                for (int r = 0; r < 2; ++r)
#pragma unroll
                    for (int c = 0; c < 2; ++c)
                        acc[r][c] = __builtin_amdgcn_mfma_f32_32x32x16_f16(fah[r][kc], fbh[c][kc], acc[r][c], 0, 0, 0);
            __builtin_amdgcn_s_setprio(0);
        }

        // 5) write next hi tile into the other buffer; single barrier per kstep
        if (kt < 7) {
            *(uint4*)&S[nxt + srow * 32 + sp]               = na0;
            *(uint4*)&S[nxt + (64 + srow) * 32 + sp]        = na1;
            *(uint4*)&S[nxt + 4096 + srow * 32 + sp]        = nb0;
            *(uint4*)&S[nxt + 4096 + (64 + srow) * 32 + sp] = nb1;
            __syncthreads();
        }
    }

    if (skip) return;
    unsigned long long* bb = best + (size_t)n * LL;
    const float s = 1.f / 4194304.f;   // 2^-22
#pragma unroll
    for (int c = 0; c < 2; ++c) {
        int m = m0 + cw + c * 32 + r5;
        unsigned long long key = 0ull;
#pragma unroll
        for (int r = 0; r < 2; ++r)
#pragma unroll
            for (int g = 0; g < 16; ++g) {
                int l = l0 + rw + r * 32 + (g & 3) + 8 * (g >> 2) + 4 * h5;
                if (l < m) {
                    float v = acc[r][c][g] * s;
                    unsigned long long k2 =
                        ((unsigned long long)f2ord(v) << 32) |
                        (unsigned long long)(0xFFFFFFFFu - (unsigned)l);
                    key = (k2 > key) ? k2 : key;
                }
            }
        unsigned long long o = __shfl_xor(key, 32, 64);
        key = (o > key) ? o : key;
        if (h5 == 0 && key != 0ull) atomicMax(bb + m, key);
    }
}

// Kernel 3: unpack best, write S, U, ref_unfold, arg (float values), m==0 overrides.
__global__ __launch_bounds__(256) void writeout(const float* __restrict__ yhat,
                                                const float* __restrict__ yprob,
                                                const unsigned long long* __restrict__ best,
                                                float* __restrict__ out) {
    int blk = blockIdx.x;                     // 0..4095
    int xcd = blk & 7;
    int n = xcd >> 1;
    int idx = (blk >> 3) + (xcd & 1) * 512;   // 0..1023
    int mb = idx >> 4;                        // 0..63
    int fc = idx & 15;                        // channel group of 4
    int tid = threadIdx.x;
    int mm = tid & 63;
    int fs = tid >> 6;                        // 0..3
    int c = fc * 4 + fs;
    int m = mb * 64 + mm;

    unsigned long long key = best[(size_t)n * LL + m];
    unsigned l = 0xFFFFFFFFu - (unsigned)(key & 0xFFFFFFFFull);
    float val = ord2f((unsigned)(key >> 32));
    bool zero = (m == 0);
    if (zero) l = 0;
    int ly = (int)(l >> 6), lx = (int)(l & 63);

    float* Sout = out;                       // [4,1,64,64]
    float* Uout = out + 16384;               // [4,1,64,64]
    float* Rout = out + 32768;               // [4,576,4096]
    float* Aout = out + 9469952;             // [4,4096] as float values

    if (fc == 0 && fs == 0) {
        float S = zero ? 1e-8f : fminf(fmaxf(val, 1e-8f), 1.0f);
        float U = zero ? 1e-8f : fminf(fmaxf(yprob[(size_t)n * LL + l], 1e-8f), 1.0f);
        Sout[(size_t)n * LL + m] = S;
        Uout[(size_t)n * LL + m] = U;
        Aout[(size_t)n * LL + m] = zero ? -1.0f : (float)l;
    }

    const float* src = yhat + (size_t)n * (Cc * LL);
    const float* plane = src + (size_t)c * LL;
    float* dst = Rout + (size_t)n * (576 * LL) + m;
    bool fast = (!zero) && (lx >= 1) && (lx <= 61);
#pragma unroll
    for (int r3 = 0; r3 < 3; ++r3) {
        int yy = ly + r3 - 1;
        bool rowok = (!zero) && (yy >= 0) && (yy < 64);
        float t0 = 0.f, t1 = 0.f, t2 = 0.f;
        if (rowok) {
            if (fast) {
                f4a v = *(const f4a*)(plane + yy * 64 + lx - 1);
                t0 = v.x; t1 = v.y; t2 = v.z;
            } else {
                if (lx > 0)  t0 = plane[yy * 64 + lx - 1];
                t1 = plane[yy * 64 + lx];
                if (lx < 63) t2 = plane[yy * 64 + lx + 1];
            }
        }
        size_t f = (size_t)(c * 9 + r3 * 3) * LL;
        __builtin_nontemporal_store(t0, dst + f);
        __builtin_nontemporal_store(t1, dst + f + LL);
        __builtin_nontemporal_store(t2, dst + f + 2 * (size_t)LL);
    }
}

extern "C" void kernel_launch(void* const* d_in, const int* in_sizes, int n_in,
                              void* d_out, int out_size, void* d_ws, size_t ws_size,
                              hipStream_t stream) {
    const float* yhat  = (const float*)d_in[0];
    const float* yprob = (const float*)d_in[1];
    float* out = (float*)d_out;

    unsigned short* VhT = (unsigned short*)d_ws;                       // 8 MiB
    unsigned short* VlT = (unsigned short*)((char*)d_ws + 8388608);    // 8 MiB (fragment-packed)
    unsigned long long* best =
        (unsigned long long*)((char*)d_ws + 16777216);                 // 128 KiB

    build_v<<<1024, 256, 0, stream>>>(yhat, VhT, VlT, best);
    simmax<<<Nn * TRI2, 256, 0, stream>>>(VhT, VlT, best);
    writeout<<<4096, 256, 0, stream>>>(yhat, yprob, best, out);
}

// Round 2
// 152.652 us; speedup vs baseline: 1.0131x; 1.0124x over previous
//
#include <hip/hip_runtime.h>
#include <stdint.h>

#define Nn 4
#define Cc 64
#define LL 4096   // H*W
#define KK 256    // feature dim: 64 channels * 4 causal taps
#define TRI2 528  // 32*33/2 triangular 128x128 tile pairs per batch

typedef _Float16 half8 __attribute__((ext_vector_type(8)));
typedef float f32x16 __attribute__((ext_vector_type(16)));
typedef float f4a __attribute__((ext_vector_type(4), aligned(4)));
typedef unsigned short ushort8v __attribute__((ext_vector_type(8)));

__device__ __forceinline__ unsigned f2ord(float f) {
    unsigned u = __float_as_uint(f);
    return u ^ ((u & 0x80000000u) ? 0xFFFFFFFFu : 0x80000000u);
}
__device__ __forceinline__ float ord2f(unsigned o) {
    unsigned u = (o & 0x80000000u) ? (o ^ 0x80000000u) : ~o;
    return __uint_as_float(u);
}
__device__ __forceinline__ unsigned short h2u(_Float16 h) {
    union { _Float16 f; unsigned short u; } x; x.f = h; return x.u;
}

// Kernel 1: normalized masked context vectors, split fp16 hi/lo, both pre-scaled:
//   Vh' = 2048*fp16(v)  (exact pow2),  Vl = fp16((v - fp16(v)) * 2048)
// BOTH buffers are MFMA-FRAGMENT-PACKED so simmax loads ALL operands straight
// from L2 (no LDS staging at all):
//   addr(n,l,k) = (((n*128 + (l>>5))*16 + (k>>4)) << 9) + ((k>>3)&1)*256 + (l&31)*8 + (k&7)
//   i.e. per (rowblk32, k16-chunk) a 1KB block where MFMA lane = (k8half)*32 + row
//   reads its half8 at blockbase + lane*16B (identity mapping, coalesced 1KB/instr).
// Each thread owns one full k16-chunk for its row -> 4 dense 16B stores; lanes at
// tid-stride-16 complete full 64B lines.
// XCD-pinned and zeroes its slice of `best`.
__global__ __launch_bounds__(256) void build_v(const float* __restrict__ yhat,
                                               unsigned short* __restrict__ VhT,
                                               unsigned short* __restrict__ VlT,
                                               unsigned long long* __restrict__ best) {
    int blk = blockIdx.x;                       // 0..1023
    int xcd = blk & 7;
    int n = xcd >> 1;
    int i64 = (blk >> 3) + (xcd & 1) * 128;     // 0..255; block covers l = i64*16 ..+16
    int tid = threadIdx.x;
    if (tid < 16) best[(size_t)n * LL + i64 * 16 + tid] = 0ull;

    int cg = tid & 15;           // channel group 0..15 (4 channels each) == k16 chunk
    int l = i64 * 16 + (tid >> 4);
    int y = l >> 6, x = l & 63;
    const float* src = yhat + (size_t)n * (Cc * LL);

    float vals[16];
    float sumsq = 0.f;
#pragma unroll
    for (int ci = 0; ci < 4; ++ci) {
        const float* p = src + (cg * 4 + ci) * LL;
        float t0 = (y > 0 && x > 0)  ? p[l - 65] : 0.f;
        float t1 = (y > 0)           ? p[l - 64] : 0.f;
        float t2 = (y > 0 && x < 63) ? p[l - 63] : 0.f;
        float t3 = (x > 0)           ? p[l - 1]  : 0.f;
        vals[ci * 4 + 0] = t0; vals[ci * 4 + 1] = t1;
        vals[ci * 4 + 2] = t2; vals[ci * 4 + 3] = t3;
        sumsq += t0 * t0 + t1 * t1 + t2 * t2 + t3 * t3;
    }
    sumsq += __shfl_xor(sumsq, 1, 64);
    sumsq += __shfl_xor(sumsq, 2, 64);
    sumsq += __shfl_xor(sumsq, 4, 64);
    sumsq += __shfl_xor(sumsq, 8, 64);
    float inv = 1.f / fmaxf(sqrtf(sumsq), 1e-12f);

    // fragment-packed destination: 1KB chunk (rowblk,cg) + row slot
    size_t pk = ((((size_t)n * 128 + (l >> 5)) * 16 + cg) << 9) + (l & 31) * 8;
    unsigned short* dh = VhT + pk;
    unsigned short* dl = VlT + pk;
    ushort8v hA, hB, lA, lB;
#pragma unroll
    for (int kk = 0; kk < 16; ++kk) {           // kk = ci*4 + tp = k within chunk
        float v = vals[kk] * inv;
        _Float16 h = (fabsf(v) < 6.1035e-5f) ? (_Float16)0 : (_Float16)v;
        _Float16 lo = (_Float16)((v - (float)h) * 2048.0f);
        unsigned short hu = h2u(h * (_Float16)2048.0f);   // exact pow2 scale
        unsigned short lu = h2u(lo);
        if (kk < 8) { hA[kk] = hu; lA[kk] = lu; }
        else        { hB[kk - 8] = hu; lB[kk - 8] = lu; }
    }
    *(ushort8v*)(dh)       = hA;   // k8-half 0
    *(ushort8v*)(dh + 256) = hB;   // k8-half 1 (+256 halves = +512B)
    *(ushort8v*)(dl)       = lA;
    *(ushort8v*)(dl + 256) = lB;
}

// Kernel 2: triangular 128x128-tiled similarity-max via split-fp16 32x32x16 MFMA.
// acc = Al'Bh' + Ah'Bl + Ah'Bh' = 2^22 * v1.v2 ; val = acc * 2^-22.
// NO LDS, NO BARRIERS: all 16 operand fragments per kstep are loaded per-lane
// direct from the fragment-packed Vh/Vl in L2 (1KB coalesced per instruction).
// Waves are fully independent; skip-wave exits immediately.
// Accumulation order and operand values preserved bit-exactly vs prior version.
// 32x32x16 layouts: A/B row(col)=lane&31, k=(lane>>5)*8+j;
// C/D: col=lane&31, row=(reg&3)+8*(reg>>2)+4*(lane>>5).
__global__ __launch_bounds__(256) void simmax(const unsigned short* __restrict__ Vh,
                                              const unsigned short* __restrict__ Vl,
                                              unsigned long long* __restrict__ best) {
    int bx = blockIdx.x;              // 0..2111
    int xcd = bx & 7, idx = bx >> 3;  // XCD-pin: each XCD owns half of one batch
    int n = xcd >> 1;
    int t = (xcd & 1) * 264 + idx;    // 0..527
    int j = (int)((sqrtf(8.f * (float)t + 1.f) - 1.f) * 0.5f);
    while ((j + 1) * (j + 2) / 2 <= t) ++j;
    while (j * (j + 1) / 2 > t) --j;
    int i = t - j * (j + 1) / 2;
    int l0 = i * 128, m0 = j * 128;

    int tid = threadIdx.x;
    int w = tid >> 6, lane = tid & 63;
    int r5 = lane & 31, h5 = lane >> 5;
    int rw = (w & 1) * 64;    // wave rows (l)
    int cw = (w >> 1) * 64;   // wave cols (m)
    if ((i == j) && (rw == 64) && (cw == 0)) return;  // fully l>m: nothing to do

    const unsigned short* VhB = Vh + (size_t)n * (LL * KK);
    const unsigned short* VlB = Vl + (size_t)n * (LL * KK);

    // fragment bases: chunk index = (rowblk*16 + k16), 1KB (512 halves) each;
    // lane's half8 at blockbase + lane*16B.
    const unsigned short* A_hi = VhB + ((size_t)((l0 + rw) >> 5) << 13) + lane * 8;
    const unsigned short* A_lo = VlB + ((size_t)((l0 + rw) >> 5) << 13) + lane * 8;
    const unsigned short* B_hi = VhB + ((size_t)((m0 + cw) >> 5) << 13) + lane * 8;
    const unsigned short* B_lo = VlB + ((size_t)((m0 + cw) >> 5) << 13) + lane * 8;

    f32x16 acc[2][2];
#pragma unroll
    for (int r = 0; r < 2; ++r)
#pragma unroll
        for (int c = 0; c < 2; ++c) acc[r][c] = (f32x16)0.f;

#pragma unroll 1
    for (int kb = 0; kb < 16; kb += 2) {       // k16-chunk pairs (kstep K=32)
        half8 fal[2][2], fah[2][2], fbl[2][2], fbh[2][2];
        // load in first-use order: pass1 needs fal,fbh; then fah,fbl
#pragma unroll
        for (int kc = 0; kc < 2; ++kc)
#pragma unroll
            for (int r = 0; r < 2; ++r) {
                fal[r][kc] = *(const half8*)(A_lo + ((r * 16 + kb + kc) << 9));
                fbh[r][kc] = *(const half8*)(B_hi + ((r * 16 + kb + kc) << 9));
            }
#pragma unroll
        for (int kc = 0; kc < 2; ++kc)
#pragma unroll
            for (int r = 0; r < 2; ++r) {
                fah[r][kc] = *(const half8*)(A_hi + ((r * 16 + kb + kc) << 9));
                fbl[r][kc] = *(const half8*)(B_lo + ((r * 16 + kb + kc) << 9));
            }

        // MFMA cluster — accumulation order identical to prior version
        __builtin_amdgcn_s_setprio(1);
#pragma unroll
        for (int kc = 0; kc < 2; ++kc)
#pragma unroll
            for (int r = 0; r < 2; ++r)
#pragma unroll
                for (int c = 0; c < 2; ++c)
                    acc[r][c] = __builtin_amdgcn_mfma_f32_32x32x16_f16(fal[r][kc], fbh[c][kc], acc[r][c], 0, 0, 0);
#pragma unroll
        for (int kc = 0; kc < 2; ++kc)
#pragma unroll
            for (int r = 0; r < 2; ++r)
#pragma unroll
                for (int c = 0; c < 2; ++c)
                    acc[r][c] = __builtin_amdgcn_mfma_f32_32x32x16_f16(fah[r][kc], fbl[c][kc], acc[r][c], 0, 0, 0);
#pragma unroll
        for (int kc = 0; kc < 2; ++kc)
#pragma unroll
            for (int r = 0; r < 2; ++r)
#pragma unroll
                for (int c = 0; c < 2; ++c)
                    acc[r][c] = __builtin_amdgcn_mfma_f32_32x32x16_f16(fah[r][kc], fbh[c][kc], acc[r][c], 0, 0, 0);
        __builtin_amdgcn_s_setprio(0);
    }

    unsigned long long* bb = best + (size_t)n * LL;
    const float s = 1.f / 4194304.f;   // 2^-22
#pragma unroll
    for (int c = 0; c < 2; ++c) {
        int m = m0 + cw + c * 32 + r5;
        unsigned long long key = 0ull;
#pragma unroll
        for (int r = 0; r < 2; ++r)
#pragma unroll
            for (int g = 0; g < 16; ++g) {
                int l = l0 + rw + r * 32 + (g & 3) + 8 * (g >> 2) + 4 * h5;
                if (l < m) {
                    float v = acc[r][c][g] * s;
                    unsigned long long k2 =
                        ((unsigned long long)f2ord(v) << 32) |
                        (unsigned long long)(0xFFFFFFFFu - (unsigned)l);
                    key = (k2 > key) ? k2 : key;
                }
            }
        unsigned long long o = __shfl_xor(key, 32, 64);
        key = (o > key) ? o : key;
        if (h5 == 0 && key != 0ull) atomicMax(bb + m, key);
    }
}

// Kernel 3: unpack best, write S, U, ref_unfold, arg (float values), m==0 overrides.
__global__ __launch_bounds__(256) void writeout(const float* __restrict__ yhat,
                                                const float* __restrict__ yprob,
                                                const unsigned long long* __restrict__ best,
                                                float* __restrict__ out) {
    int blk = blockIdx.x;                     // 0..4095
    int xcd = blk & 7;
    int n = xcd >> 1;
    int idx = (blk >> 3) + (xcd & 1) * 512;   // 0..1023
    int mb = idx >> 4;                        // 0..63
    int fc = idx & 15;                        // channel group of 4
    int tid = threadIdx.x;
    int mm = tid & 63;
    int fs = tid >> 6;                        // 0..3
    int c = fc * 4 + fs;
    int m = mb * 64 + mm;

    unsigned long long key = best[(size_t)n * LL + m];
    unsigned l = 0xFFFFFFFFu - (unsigned)(key & 0xFFFFFFFFull);
    float val = ord2f((unsigned)(key >> 32));
    bool zero = (m == 0);
    if (zero) l = 0;
    int ly = (int)(l >> 6), lx = (int)(l & 63);

    float* Sout = out;                       // [4,1,64,64]
    float* Uout = out + 16384;               // [4,1,64,64]
    float* Rout = out + 32768;               // [4,576,4096]
    float* Aout = out + 9469952;             // [4,4096] as float values

    if (fc == 0 && fs == 0) {
        float S = zero ? 1e-8f : fminf(fmaxf(val, 1e-8f), 1.0f);
        float U = zero ? 1e-8f : fminf(fmaxf(yprob[(size_t)n * LL + l], 1e-8f), 1.0f);
        Sout[(size_t)n * LL + m] = S;
        Uout[(size_t)n * LL + m] = U;
        Aout[(size_t)n * LL + m] = zero ? -1.0f : (float)l;
    }

    const float* src = yhat + (size_t)n * (Cc * LL);
    const float* plane = src + (size_t)c * LL;
    float* dst = Rout + (size_t)n * (576 * LL) + m;
    bool fast = (!zero) && (lx >= 1) && (lx <= 61);
#pragma unroll
    for (int r3 = 0; r3 < 3; ++r3) {
        int yy = ly + r3 - 1;
        bool rowok = (!zero) && (yy >= 0) && (yy < 64);
        float t0 = 0.f, t1 = 0.f, t2 = 0.f;
        if (rowok) {
            if (fast) {
                f4a v = *(const f4a*)(plane + yy * 64 + lx - 1);
                t0 = v.x; t1 = v.y; t2 = v.z;
            } else {
                if (lx > 0)  t0 = plane[yy * 64 + lx - 1];
                t1 = plane[yy * 64 + lx];
                if (lx < 63) t2 = plane[yy * 64 + lx + 1];
            }
        }
        size_t f = (size_t)(c * 9 + r3 * 3) * LL;
        __builtin_nontemporal_store(t0, dst + f);
        __builtin_nontemporal_store(t1, dst + f + LL);
        __builtin_nontemporal_store(t2, dst + f + 2 * (size_t)LL);
    }
}

extern "C" void kernel_launch(void* const* d_in, const int* in_sizes, int n_in,
                              void* d_out, int out_size, void* d_ws, size_t ws_size,
                              hipStream_t stream) {
    const float* yhat  = (const float*)d_in[0];
    const float* yprob = (const float*)d_in[1];
    float* out = (float*)d_out;

    unsigned short* VhT = (unsigned short*)d_ws;                       // 8 MiB (fragment-packed)
    unsigned short* VlT = (unsigned short*)((char*)d_ws + 8388608);    // 8 MiB (fragment-packed)
    unsigned long long* best =
        (unsigned long long*)((char*)d_ws + 16777216);                 // 128 KiB

    build_v<<<1024, 256, 0, stream>>>(yhat, VhT, VlT, best);
    simmax<<<Nn * TRI2, 256, 0, stream>>>(VhT, VlT, best);
    writeout<<<4096, 256, 0, stream>>>(yhat, yprob, best, out);
}